// Round 1
// 531.557 us; speedup vs baseline: 1.1309x; 1.1309x over previous
//
#include <hip/hip_runtime.h>
#include <stdint.h>
#include <math.h>

#define GM 8192   // rows of x / out
#define GN 4096   // D_OUT
#define GK 4096   // D_IN

// ---- GEMM geometry: 256^2 8-phase template (learn_hip m201) ----
#define BM 256
#define BN 256
#define BK 64
#define NT (GK / BK)   // 64 K-steps

typedef __bf16 bf16x8 __attribute__((ext_vector_type(8)));
typedef float  f32x4  __attribute__((ext_vector_type(4)));

typedef const __attribute__((address_space(1))) void* gas_ptr;
typedef __attribute__((address_space(3))) void* las_ptr;

__device__ __forceinline__ unsigned short f2bf(float f) {
    union { float f; unsigned u; } a; a.f = f;
    unsigned r = a.u + 0x7FFFu + ((a.u >> 16) & 1u);  // RNE
    return (unsigned short)(r >> 16);
}
__device__ __forceinline__ float bf2f(unsigned short h) {
    union { unsigned u; float f; } a; a.u = ((unsigned)h) << 16;
    return a.f;
}

// fast tanh via v_exp_f32; |err| ~1e-7 abs, exact saturation for big x
__device__ __forceinline__ float fast_tanh(float x) {
    float xc = fminf(fmaxf(x, -15.f), 15.f);
    float e = __expf(2.f * xc);
    return (e - 1.f) * __builtin_amdgcn_rcpf(e + 1.f);
}
// fast atanh for 0 <= x <= 0.996
__device__ __forceinline__ float fast_atanh(float x) {
    return 0.5f * __logf((1.f + x) * __builtin_amdgcn_rcpf(1.f - x));
}

// ------- pre-pass, barrier-free: one WAVE per row ---------------------------
// blocks [0,2048): x rows (4 rows/block, 1/wave, logmap0 prescale -> bf16)
// blocks [2048,3072): W rows (4 rows/block, 1/wave, f32 -> bf16 stream cast)
__global__ __launch_bounds__(256) void pre_kernel(const float* __restrict__ x,
                                                  const float* __restrict__ W,
                                                  unsigned short* __restrict__ t,
                                                  unsigned short* __restrict__ Wb) {
    const int lane = threadIdx.x & 63;
    const int wv   = threadIdx.x >> 6;
    if (blockIdx.x < 2048) {
        const int row = blockIdx.x * 4 + wv;
        const float* xr = x + (size_t)row * GK;
        float v[64];
        float ss = 0.f;
#pragma unroll
        for (int j = 0; j < 16; ++j) {
            f32x4 p = *(const f32x4*)(xr + (size_t)(j * 64 + lane) * 4);
#pragma unroll
            for (int e = 0; e < 4; ++e) { v[j * 4 + e] = p[e]; ss += p[e] * p[e]; }
        }
#pragma unroll
        for (int off = 32; off; off >>= 1) ss += __shfl_xor(ss, off);
        const float n = fmaxf(sqrtf(ss), 1e-15f);
        const float scale = fast_atanh(fminf(n, 1.f - 1e-7f)) * __builtin_amdgcn_rcpf(n);
        unsigned short* tr = t + (size_t)row * GK;
#pragma unroll
        for (int j = 0; j < 16; ++j) {
            ushort4 o;
            o.x = f2bf(v[j * 4 + 0] * scale);
            o.y = f2bf(v[j * 4 + 1] * scale);
            o.z = f2bf(v[j * 4 + 2] * scale);
            o.w = f2bf(v[j * 4 + 3] * scale);
            *(ushort4*)(tr + (size_t)(j * 64 + lane) * 4) = o;
        }
    } else {
        const int row = (blockIdx.x - 2048) * 4 + wv;
        const float* wr = W + (size_t)row * GK;
        unsigned short* wo = Wb + (size_t)row * GK;
#pragma unroll 4
        for (int j = 0; j < 16; ++j) {
            f32x4 p = *(const f32x4*)(wr + (size_t)(j * 64 + lane) * 4);
            ushort4 o;
            o.x = f2bf(p[0]); o.y = f2bf(p[1]); o.z = f2bf(p[2]); o.w = f2bf(p[3]);
            *(ushort4*)(wo + (size_t)(j * 64 + lane) * 4) = o;
        }
    }
}

// ---------------- GEMM: C[M,N] = A[M,K] * B[N,K]^T  (bf16 in) ---------------
// 256x256 tile, BK=64, 8 waves (2Mx4N), 128 KiB LDS double-buffer.
// 4 phases per K-tile, ks-major so ks0 regions die after phase 2 -> deep
// prefetch (counted vmcnt(8), never 0). LDS layout [buf][mat][kh][256][32],
// XOR swizzle slot^((row>>1)&3) applied on pre-swizzled global source AND
// ds_read address (both-sides, rule 21). setprio(1) around MFMA clusters.
// Accumulation order per C element identical to previous kernel (sequential K).
template <bool BF16C>
__global__ __launch_bounds__(512, 2) void gemm_kernel(const unsigned short* __restrict__ A,
                                                      const unsigned short* __restrict__ B,
                                                      void* __restrict__ Cv) {
    __shared__ __align__(16) unsigned short lds[65536];  // 128 KiB

    const int tid  = threadIdx.x;
    const int w    = tid >> 6;
    const int lane = tid & 63;
    const int m16  = lane & 15;
    const int quad = lane >> 4;

    // XCD-aware bijective swizzle: nwg=512, 8 XCDs, cpx=64
    const int bid = blockIdx.x;
    const int wid = (bid & 7) * 64 + (bid >> 3);
    const int tileM = (wid >> 4) * BM;   // 32 M-tiles (M-major within XCD chunk)
    const int tileN = (wid & 15) * BN;   // 16 N-tiles

    const int waveM = (w >> 2) * 128;    // 2 wave-rows  -> per-wave 128 M
    const int waveN = (w & 3) * 64;      // 4 wave-cols  -> per-wave 64 N

    // ---- staging source addresses (pre-swizzled global, linear LDS dest) ----
    // chunk c = j*8 + w covers rows [16c,16c+16) of one K-half block.
    const int rS   = w * 16 + (lane >> 2);        // row for j=0 chunk (0..127)
    const int swzS = (rS >> 1) & 3;               // same for rS+128 (bit const)
    const int colS = ((lane & 3) ^ swzS) * 8;     // bf16 col within 32-col half
    const unsigned short* a0 = A + (size_t)(tileM + rS) * GK + colS;
    const unsigned short* a1 = a0 + (size_t)128 * GK;
    const unsigned short* b0 = B + (size_t)(tileN + rS) * GK + colS;
    const unsigned short* b1 = b0 + (size_t)128 * GK;

#define STAGE(DBUF, MAT, KH, KEL)                                                                      \
    do {                                                                                               \
        const int _off = (DBUF) * 65536 + (MAT) * 32768 + (KH) * 16384 + w * 1024;                     \
        const unsigned short* _s0 = ((MAT) ? b0 : a0) + (KEL) + (KH) * 32;                             \
        const unsigned short* _s1 = ((MAT) ? b1 : a1) + (KEL) + (KH) * 32;                             \
        __builtin_amdgcn_global_load_lds((gas_ptr)_s0, (las_ptr)((char*)lds + _off), 16, 0, 0);        \
        __builtin_amdgcn_global_load_lds((gas_ptr)_s1, (las_ptr)((char*)lds + _off + 8192), 16, 0, 0); \
    } while (0)

    // ---- fragment LDS byte offsets (within a 16 KiB (buf,mat,kh) block) ----
    int aoff[8], boff[4];
#pragma unroll
    for (int mi = 0; mi < 8; ++mi) {
        const int r = waveM + mi * 16 + m16;
        aoff[mi] = r * 64 + ((quad ^ ((r >> 1) & 3)) << 4);
    }
#pragma unroll
    for (int ni = 0; ni < 4; ++ni) {
        const int r = waveN + ni * 16 + m16;
        boff[ni] = r * 64 + ((quad ^ ((r >> 1) & 3)) << 4);
    }

#define FRAG(OFF) (*(const bf16x8*)((const char*)lds + (OFF)))

#define MFMA_BLOCK(MBASE)                                                            \
    {                                                                                \
        _Pragma("unroll")                                                            \
        for (int mi = 0; mi < 4; ++mi) {                                             \
            _Pragma("unroll")                                                        \
            for (int ni = 0; ni < 4; ++ni)                                           \
                acc[(MBASE) + mi][ni] = __builtin_amdgcn_mfma_f32_16x16x32_bf16(     \
                    af[mi], bf[ni], acc[(MBASE) + mi][ni], 0, 0, 0);                 \
        }                                                                            \
    }

    f32x4 acc[8][4] = {};
    bf16x8 af[4], bf[4];

    // ---- prologue: issue 6 half-tiles (t0.A0 B0 A1 B1, t1.A0 B0) = 12 loads ----
    STAGE(0, 0, 0, 0);
    STAGE(0, 1, 0, 0);
    STAGE(0, 0, 1, 0);
    STAGE(0, 1, 1, 0);
    STAGE(1, 0, 0, BK);
    STAGE(1, 1, 0, BK);
    asm volatile("s_waitcnt vmcnt(8)" ::: "memory");   // t0.A0,t0.B0 landed
    __builtin_amdgcn_s_barrier();

#pragma unroll 2
    for (int t = 0; t < NT; ++t) {
        const int b  = t & 1;
        const int bn = b ^ 1;
        const int abase0 = b * 65536;           // A ks0 block
        const int abase1 = abase0 + 16384;      // A ks1
        const int bbase0 = abase0 + 32768;      // B ks0
        const int bbase1 = bbase0 + 16384;      // B ks1
        const int k1 = (t + 1 < NT ? t + 1 : NT - 1) * BK;  // clamped: redundant
        const int k2 = (t + 2 < NT ? t + 2 : NT - 1) * BK;  // tail loads hit dead regions

        // phase 1: ks0, acc rows 0-3 | prefetch (t+1).A-kh1 -> buf bn (dead since t-1.ph4)
        af[0] = FRAG(abase0 + aoff[0]); af[1] = FRAG(abase0 + aoff[1]);
        af[2] = FRAG(abase0 + aoff[2]); af[3] = FRAG(abase0 + aoff[3]);
        bf[0] = FRAG(bbase0 + boff[0]); bf[1] = FRAG(bbase0 + boff[1]);
        bf[2] = FRAG(bbase0 + boff[2]); bf[3] = FRAG(bbase0 + boff[3]);
        STAGE(bn, 0, 1, k1);
        __builtin_amdgcn_s_barrier();
        asm volatile("s_waitcnt lgkmcnt(0)" ::: "memory");
        __builtin_amdgcn_s_setprio(1);
        MFMA_BLOCK(0);
        __builtin_amdgcn_s_setprio(0);
        __builtin_amdgcn_s_barrier();

        // phase 2: ks0, acc rows 4-7 (reuse bf) | prefetch (t+1).B-kh1
        af[0] = FRAG(abase0 + aoff[4]); af[1] = FRAG(abase0 + aoff[5]);
        af[2] = FRAG(abase0 + aoff[6]); af[3] = FRAG(abase0 + aoff[7]);
        STAGE(bn, 1, 1, k1);
        __builtin_amdgcn_s_barrier();
        asm volatile("s_waitcnt lgkmcnt(0)" ::: "memory");
        __builtin_amdgcn_s_setprio(1);
        MFMA_BLOCK(4);
        __builtin_amdgcn_s_setprio(0);
        asm volatile("s_waitcnt vmcnt(8)" ::: "memory");  // gates ph3's ks1 reads
        __builtin_amdgcn_s_barrier();

        // phase 3: ks1, acc rows 0-3 | prefetch (t+2).A-kh0 into CURRENT buf (kh0 dead)
        af[0] = FRAG(abase1 + aoff[0]); af[1] = FRAG(abase1 + aoff[1]);
        af[2] = FRAG(abase1 + aoff[2]); af[3] = FRAG(abase1 + aoff[3]);
        bf[0] = FRAG(bbase1 + boff[0]); bf[1] = FRAG(bbase1 + boff[1]);
        bf[2] = FRAG(bbase1 + boff[2]); bf[3] = FRAG(bbase1 + boff[3]);
        STAGE(b, 0, 0, k2);
        __builtin_amdgcn_s_barrier();
        asm volatile("s_waitcnt lgkmcnt(0)" ::: "memory");
        __builtin_amdgcn_s_setprio(1);
        MFMA_BLOCK(0);
        __builtin_amdgcn_s_setprio(0);
        __builtin_amdgcn_s_barrier();

        // phase 4: ks1, acc rows 4-7 | prefetch (t+2).B-kh0
        af[0] = FRAG(abase1 + aoff[4]); af[1] = FRAG(abase1 + aoff[5]);
        af[2] = FRAG(abase1 + aoff[6]); af[3] = FRAG(abase1 + aoff[7]);
        STAGE(b, 1, 0, k2);
        __builtin_amdgcn_s_barrier();
        asm volatile("s_waitcnt lgkmcnt(0)" ::: "memory");
        __builtin_amdgcn_s_setprio(1);
        MFMA_BLOCK(4);
        __builtin_amdgcn_s_setprio(0);
        asm volatile("s_waitcnt vmcnt(8)" ::: "memory");  // gates next tile's ks0 reads
        __builtin_amdgcn_s_barrier();
    }

    // C/D layout: col = lane&15, row = quad*4 + reg  [verified m89/m91]
#pragma unroll
    for (int mi = 0; mi < 8; ++mi)
#pragma unroll
        for (int ni = 0; ni < 4; ++ni)
#pragma unroll
            for (int r = 0; r < 4; ++r) {
                const int row = tileM + waveM + mi * 16 + quad * 4 + r;
                const int col = tileN + waveN + ni * 16 + m16;
                if (BF16C)
                    ((unsigned short*)Cv)[(size_t)row * GN + col] = f2bf(acc[mi][ni][r]);
                else
                    ((float*)Cv)[(size_t)row * GN + col] = acc[mi][ni][r];
            }
#undef STAGE
#undef FRAG
#undef MFMA_BLOCK
}

// ---------------- fused epilogue, barrier-free: one WAVE per row ------------
// u = C_row + b;  y = proj(expmap0(u));  t2 = tanh(logmap0(y));  out = proj(expmap0(t2))
template <bool BF16C>
__global__ __launch_bounds__(256) void epilogue_kernel(const void* __restrict__ Cv,
                                                       const float* __restrict__ bias,
                                                       float* __restrict__ out) {
    const int lane = threadIdx.x & 63;
    const int row  = blockIdx.x * 4 + (threadIdx.x >> 6);
    float u[64];
    float ss = 0.f;
#pragma unroll
    for (int j = 0; j < 16; ++j) {
        const size_t col = (size_t)(j * 64 + lane) * 4;
        f32x4 bb = *(const f32x4*)(bias + col);
        if (BF16C) {
            ushort4 p = *(const ushort4*)((const unsigned short*)Cv + (size_t)row * GN + col);
            float q0 = bf2f(p.x) + bb[0], q1 = bf2f(p.y) + bb[1];
            float q2 = bf2f(p.z) + bb[2], q3 = bf2f(p.w) + bb[3];
            u[j * 4 + 0] = q0; u[j * 4 + 1] = q1; u[j * 4 + 2] = q2; u[j * 4 + 3] = q3;
            ss += q0 * q0 + q1 * q1 + q2 * q2 + q3 * q3;
        } else {
            f32x4 p = *(const f32x4*)((const float*)Cv + (size_t)row * GN + col);
#pragma unroll
            for (int e = 0; e < 4; ++e) { float q = p[e] + bb[e]; u[j * 4 + e] = q; ss += q * q; }
        }
    }
#pragma unroll
    for (int off = 32; off; off >>= 1) ss += __shfl_xor(ss, off);

    const float n1 = fmaxf(sqrtf(ss), 1e-15f);
    const float ny = fminf(fast_tanh(n1), 0.996f);        // ||proj(expmap0(u))||
    // combined: y_i = u_i*ny/n1 ; l_i = y_i*atanh(ny)/ny  => l_i = u_i*g
    const float g = (ny * __builtin_amdgcn_rcpf(n1)) *
                    (fast_atanh(ny) * __builtin_amdgcn_rcpf(fmaxf(ny, 1e-15f)));

    float ss2 = 0.f;
#pragma unroll
    for (int i = 0; i < 64; ++i) { float q = fast_tanh(u[i] * g); u[i] = q; ss2 += q * q; }
#pragma unroll
    for (int off = 32; off; off >>= 1) ss2 += __shfl_xor(ss2, off);

    const float n3 = fmaxf(sqrtf(ss2), 1e-15f);
    const float s3 = fminf(fast_tanh(n3), 0.996f) * __builtin_amdgcn_rcpf(n3);
    float* orow = out + (size_t)row * GN;
#pragma unroll
    for (int j = 0; j < 16; ++j) {
        f32x4 o;
#pragma unroll
        for (int e = 0; e < 4; ++e) o[e] = u[j * 4 + e] * s3;
        *(f32x4*)(orow + (size_t)(j * 64 + lane) * 4) = o;
    }
}

extern "C" void kernel_launch(void* const* d_in, const int* in_sizes, int n_in,
                              void* d_out, int out_size, void* d_ws, size_t ws_size,
                              hipStream_t stream) {
    const float* x = (const float*)d_in[0];
    const float* W = (const float*)d_in[1];
    const float* b = (const float*)d_in[2];
    float* out = (float*)d_out;

    // ws layout: t_bf16 (64 MiB) | W_bf16 (32 MiB) | [optional] C_bf16 (64 MiB)
    unsigned short* t_bf = (unsigned short*)d_ws;
    unsigned short* W_bf = t_bf + (size_t)GM * GK;
    unsigned short* C_bf = W_bf + (size_t)GN * GK;
    const size_t need_bf16c = ((size_t)GM * GK + (size_t)GN * GK + (size_t)GM * GN) * 2;
    const bool bf16c = ws_size >= need_bf16c;   // ws_size fixed -> same path every call

    pre_kernel<<<2048 + 1024, 256, 0, stream>>>(x, W, t_bf, W_bf);
    const int nwg = (GM / BM) * (GN / BN);      // 32*16 = 512, divisible by 8
    if (bf16c) {
        gemm_kernel<true><<<nwg, 512, 0, stream>>>(t_bf, W_bf, (void*)C_bf);
        epilogue_kernel<true><<<2048, 256, 0, stream>>>((const void*)C_bf, b, out);
    } else {
        gemm_kernel<false><<<nwg, 512, 0, stream>>>(t_bf, W_bf, (void*)out);
        epilogue_kernel<false><<<2048, 256, 0, stream>>>((const void*)out, b, out);
    }
}

// Round 2
// 521.449 us; speedup vs baseline: 1.1528x; 1.0194x over previous
//
#include <hip/hip_runtime.h>
#include <stdint.h>
#include <math.h>

#define GM 8192   // rows of x / out
#define GN 4096   // D_OUT
#define GK 4096   // D_IN

// ---- GEMM geometry: 256^2 template (learn_hip m201), 1-barrier phases ----
#define BM 256
#define BN 256
#define BK 64
#define NT (GK / BK)   // 64 K-steps

typedef __bf16 bf16x8 __attribute__((ext_vector_type(8)));
typedef float  f32x4  __attribute__((ext_vector_type(4)));

typedef const __attribute__((address_space(1))) void* gas_ptr;
typedef __attribute__((address_space(3))) void* las_ptr;

__device__ __forceinline__ unsigned short f2bf(float f) {
    union { float f; unsigned u; } a; a.f = f;
    unsigned r = a.u + 0x7FFFu + ((a.u >> 16) & 1u);  // RNE
    return (unsigned short)(r >> 16);
}
__device__ __forceinline__ float bf2f(unsigned short h) {
    union { unsigned u; float f; } a; a.u = ((unsigned)h) << 16;
    return a.f;
}

// fast tanh via v_exp_f32; |err| ~1e-7 abs, exact saturation for big x
__device__ __forceinline__ float fast_tanh(float x) {
    float xc = fminf(fmaxf(x, -15.f), 15.f);
    float e = __expf(2.f * xc);
    return (e - 1.f) * __builtin_amdgcn_rcpf(e + 1.f);
}
// fast atanh for 0 <= x <= 0.996
__device__ __forceinline__ float fast_atanh(float x) {
    return 0.5f * __logf((1.f + x) * __builtin_amdgcn_rcpf(1.f - x));
}

// ------- pre-pass, barrier-free: one WAVE per row ---------------------------
__global__ __launch_bounds__(256) void pre_kernel(const float* __restrict__ x,
                                                  const float* __restrict__ W,
                                                  unsigned short* __restrict__ t,
                                                  unsigned short* __restrict__ Wb) {
    const int lane = threadIdx.x & 63;
    const int wv   = threadIdx.x >> 6;
    if (blockIdx.x < 2048) {
        const int row = blockIdx.x * 4 + wv;
        const float* xr = x + (size_t)row * GK;
        float v[64];
        float ss = 0.f;
#pragma unroll
        for (int j = 0; j < 16; ++j) {
            f32x4 p = *(const f32x4*)(xr + (size_t)(j * 64 + lane) * 4);
#pragma unroll
            for (int e = 0; e < 4; ++e) { v[j * 4 + e] = p[e]; ss += p[e] * p[e]; }
        }
#pragma unroll
        for (int off = 32; off; off >>= 1) ss += __shfl_xor(ss, off);
        const float n = fmaxf(sqrtf(ss), 1e-15f);
        const float scale = fast_atanh(fminf(n, 1.f - 1e-7f)) * __builtin_amdgcn_rcpf(n);
        unsigned short* tr = t + (size_t)row * GK;
#pragma unroll
        for (int j = 0; j < 16; ++j) {
            ushort4 o;
            o.x = f2bf(v[j * 4 + 0] * scale);
            o.y = f2bf(v[j * 4 + 1] * scale);
            o.z = f2bf(v[j * 4 + 2] * scale);
            o.w = f2bf(v[j * 4 + 3] * scale);
            *(ushort4*)(tr + (size_t)(j * 64 + lane) * 4) = o;
        }
    } else {
        const int row = (blockIdx.x - 2048) * 4 + wv;
        const float* wr = W + (size_t)row * GK;
        unsigned short* wo = Wb + (size_t)row * GK;
#pragma unroll 4
        for (int j = 0; j < 16; ++j) {
            f32x4 p = *(const f32x4*)(wr + (size_t)(j * 64 + lane) * 4);
            ushort4 o;
            o.x = f2bf(p[0]); o.y = f2bf(p[1]); o.z = f2bf(p[2]); o.w = f2bf(p[3]);
            *(ushort4*)(wo + (size_t)(j * 64 + lane) * 4) = o;
        }
    }
}

// ---------------- GEMM: C[M,N] = A[M,K] * B[N,K]^T  (bf16 in) ---------------
// 256x256 tile, BK=64, 8 waves (2Mx4N), 128 KiB LDS double-buffer.
// 4 phases per K-tile. CHANGES vs prev round:
//  - NO asm lgkmcnt(0): compiler emits counted lgkmcnt per MFMA operand,
//    overlapping ds_read completion with MFMA issue within each phase.
//  - ONE barrier per phase (at phase end). Sound because every region's
//    reads complete in-phase (MFMA counted-waits before the barrier) and
//    every STAGE targets a region last read >=2 phases earlier:
//      STAGE(bn,A,1)@ph1: bn.A1 last read ph3 of t-1 (2 barriers back)
//      STAGE(bn,B,1)@ph2: bn.B1 last read ph3 of t-1
//      STAGE(b ,A,0)@ph3: b.A0  last read ph2 of t  (1 barrier back) OK:
//                         reads completed before ph2-end barrier
//      STAGE(b ,B,0)@ph4: b.B0  last read ph3 of t
//  - ds_read hoisting across phases is safe: pre-ks-gate regions are
//    blocked by the vmcnt asm "memory" clobbers; others are stable data.
// vmcnt(8) gates unchanged (phases 2 and 4 only, never 0 in loop).
// Accumulation order per C element identical (sequential K).
template <bool BF16C>
__global__ __launch_bounds__(512, 2) void gemm_kernel(const unsigned short* __restrict__ A,
                                                      const unsigned short* __restrict__ B,
                                                      void* __restrict__ Cv) {
    __shared__ __align__(16) unsigned short lds[65536];  // 128 KiB

    const int tid  = threadIdx.x;
    const int w    = tid >> 6;
    const int lane = tid & 63;
    const int m16  = lane & 15;
    const int quad = lane >> 4;

    // XCD-aware bijective swizzle: nwg=512, 8 XCDs, cpx=64
    const int bid = blockIdx.x;
    const int wid = (bid & 7) * 64 + (bid >> 3);
    const int tileM = (wid >> 4) * BM;   // 32 M-tiles
    const int tileN = (wid & 15) * BN;   // 16 N-tiles

    const int waveM = (w >> 2) * 128;    // 2 wave-rows
    const int waveN = (w & 3) * 64;      // 4 wave-cols

    // ---- staging source addresses (pre-swizzled global, linear LDS dest) ----
    const int rS   = w * 16 + (lane >> 2);        // row for j=0 chunk (0..127)
    const int swzS = (rS >> 1) & 3;               // same for rS+128 (bit const)
    const int colS = ((lane & 3) ^ swzS) * 8;     // bf16 col within 32-col half
    const unsigned short* a0 = A + (size_t)(tileM + rS) * GK + colS;
    const unsigned short* a1 = a0 + (size_t)128 * GK;
    const unsigned short* b0 = B + (size_t)(tileN + rS) * GK + colS;
    const unsigned short* b1 = b0 + (size_t)128 * GK;

#define STAGE(DBUF, MAT, KH, KEL)                                                                      \
    do {                                                                                               \
        const int _off = (DBUF) * 65536 + (MAT) * 32768 + (KH) * 16384 + w * 1024;                     \
        const unsigned short* _s0 = ((MAT) ? b0 : a0) + (KEL) + (KH) * 32;                             \
        const unsigned short* _s1 = ((MAT) ? b1 : a1) + (KEL) + (KH) * 32;                             \
        __builtin_amdgcn_global_load_lds((gas_ptr)_s0, (las_ptr)((char*)lds + _off), 16, 0, 0);        \
        __builtin_amdgcn_global_load_lds((gas_ptr)_s1, (las_ptr)((char*)lds + _off + 8192), 16, 0, 0); \
    } while (0)

    // ---- fragment LDS byte offsets (within a 16 KiB (buf,mat,kh) block) ----
    int aoff[8], boff[4];
#pragma unroll
    for (int mi = 0; mi < 8; ++mi) {
        const int r = waveM + mi * 16 + m16;
        aoff[mi] = r * 64 + ((quad ^ ((r >> 1) & 3)) << 4);
    }
#pragma unroll
    for (int ni = 0; ni < 4; ++ni) {
        const int r = waveN + ni * 16 + m16;
        boff[ni] = r * 64 + ((quad ^ ((r >> 1) & 3)) << 4);
    }

#define FRAG(OFF) (*(const bf16x8*)((const char*)lds + (OFF)))

#define MFMA_BLOCK(MBASE)                                                            \
    {                                                                                \
        _Pragma("unroll")                                                            \
        for (int mi = 0; mi < 4; ++mi) {                                             \
            _Pragma("unroll")                                                        \
            for (int ni = 0; ni < 4; ++ni)                                           \
                acc[(MBASE) + mi][ni] = __builtin_amdgcn_mfma_f32_16x16x32_bf16(     \
                    af[mi], bf[ni], acc[(MBASE) + mi][ni], 0, 0, 0);                 \
        }                                                                            \
    }

    f32x4 acc[8][4] = {};
    bf16x8 af[4], bf[4];

    // ---- prologue: issue 6 half-tiles (t0.A0 B0 A1 B1, t1.A0 B0) = 12 loads ----
    STAGE(0, 0, 0, 0);
    STAGE(0, 1, 0, 0);
    STAGE(0, 0, 1, 0);
    STAGE(0, 1, 1, 0);
    STAGE(1, 0, 0, BK);
    STAGE(1, 1, 0, BK);
    asm volatile("s_waitcnt vmcnt(8)" ::: "memory");   // t0.A0,t0.B0 landed
    __builtin_amdgcn_s_barrier();

#pragma unroll 2
    for (int t = 0; t < NT; ++t) {
        const int b  = t & 1;
        const int bn = b ^ 1;
        const int abase0 = b * 65536;           // A ks0 block
        const int abase1 = abase0 + 16384;      // A ks1
        const int bbase0 = abase0 + 32768;      // B ks0
        const int bbase1 = bbase0 + 16384;      // B ks1
        const int k1 = (t + 1 < NT ? t + 1 : NT - 1) * BK;  // clamped: redundant
        const int k2 = (t + 2 < NT ? t + 2 : NT - 1) * BK;  // tail loads re-stage same bytes

        // phase 1: ks0, acc rows 0-3 | prefetch (t+1).A-kh1 -> buf bn
        af[0] = FRAG(abase0 + aoff[0]); bf[0] = FRAG(bbase0 + boff[0]);
        af[1] = FRAG(abase0 + aoff[1]); bf[1] = FRAG(bbase0 + boff[1]);
        af[2] = FRAG(abase0 + aoff[2]); bf[2] = FRAG(bbase0 + boff[2]);
        af[3] = FRAG(abase0 + aoff[3]); bf[3] = FRAG(bbase0 + boff[3]);
        STAGE(bn, 0, 1, k1);
        __builtin_amdgcn_s_setprio(1);
        MFMA_BLOCK(0);
        __builtin_amdgcn_s_setprio(0);
        __builtin_amdgcn_s_barrier();

        // phase 2: ks0, acc rows 4-7 (reuse bf) | prefetch (t+1).B-kh1
        af[0] = FRAG(abase0 + aoff[4]); af[1] = FRAG(abase0 + aoff[5]);
        af[2] = FRAG(abase0 + aoff[6]); af[3] = FRAG(abase0 + aoff[7]);
        STAGE(bn, 1, 1, k1);
        __builtin_amdgcn_s_setprio(1);
        MFMA_BLOCK(4);
        __builtin_amdgcn_s_setprio(0);
        asm volatile("s_waitcnt vmcnt(8)" ::: "memory");  // gates ph3's ks1 reads
        __builtin_amdgcn_s_barrier();

        // phase 3: ks1, acc rows 0-3 | prefetch (t+2).A-kh0 into CURRENT buf
        af[0] = FRAG(abase1 + aoff[0]); bf[0] = FRAG(bbase1 + boff[0]);
        af[1] = FRAG(abase1 + aoff[1]); bf[1] = FRAG(bbase1 + boff[1]);
        af[2] = FRAG(abase1 + aoff[2]); bf[2] = FRAG(bbase1 + boff[2]);
        af[3] = FRAG(abase1 + aoff[3]); bf[3] = FRAG(bbase1 + boff[3]);
        STAGE(b, 0, 0, k2);
        __builtin_amdgcn_s_setprio(1);
        MFMA_BLOCK(0);
        __builtin_amdgcn_s_setprio(0);
        __builtin_amdgcn_s_barrier();

        // phase 4: ks1, acc rows 4-7 | prefetch (t+2).B-kh0
        af[0] = FRAG(abase1 + aoff[4]); af[1] = FRAG(abase1 + aoff[5]);
        af[2] = FRAG(abase1 + aoff[6]); af[3] = FRAG(abase1 + aoff[7]);
        STAGE(b, 1, 0, k2);
        __builtin_amdgcn_s_setprio(1);
        MFMA_BLOCK(4);
        __builtin_amdgcn_s_setprio(0);
        asm volatile("s_waitcnt vmcnt(8)" ::: "memory");  // gates next tile's ks0 reads
        __builtin_amdgcn_s_barrier();
    }

    // C/D layout: col = lane&15, row = quad*4 + reg  [verified m89/m91]
#pragma unroll
    for (int mi = 0; mi < 8; ++mi)
#pragma unroll
        for (int ni = 0; ni < 4; ++ni)
#pragma unroll
            for (int r = 0; r < 4; ++r) {
                const int row = tileM + waveM + mi * 16 + quad * 4 + r;
                const int col = tileN + waveN + ni * 16 + m16;
                if (BF16C)
                    ((unsigned short*)Cv)[(size_t)row * GN + col] = f2bf(acc[mi][ni][r]);
                else
                    ((float*)Cv)[(size_t)row * GN + col] = acc[mi][ni][r];
            }
#undef STAGE
#undef FRAG
#undef MFMA_BLOCK
}

// ---------------- fused epilogue, barrier-free: one WAVE per row ------------
template <bool BF16C>
__global__ __launch_bounds__(256) void epilogue_kernel(const void* __restrict__ Cv,
                                                       const float* __restrict__ bias,
                                                       float* __restrict__ out) {
    const int lane = threadIdx.x & 63;
    const int row  = blockIdx.x * 4 + (threadIdx.x >> 6);
    float u[64];
    float ss = 0.f;
#pragma unroll
    for (int j = 0; j < 16; ++j) {
        const size_t col = (size_t)(j * 64 + lane) * 4;
        f32x4 bb = *(const f32x4*)(bias + col);
        if (BF16C) {
            ushort4 p = *(const ushort4*)((const unsigned short*)Cv + (size_t)row * GN + col);
            float q0 = bf2f(p.x) + bb[0], q1 = bf2f(p.y) + bb[1];
            float q2 = bf2f(p.z) + bb[2], q3 = bf2f(p.w) + bb[3];
            u[j * 4 + 0] = q0; u[j * 4 + 1] = q1; u[j * 4 + 2] = q2; u[j * 4 + 3] = q3;
            ss += q0 * q0 + q1 * q1 + q2 * q2 + q3 * q3;
        } else {
            f32x4 p = *(const f32x4*)((const float*)Cv + (size_t)row * GN + col);
#pragma unroll
            for (int e = 0; e < 4; ++e) { float q = p[e] + bb[e]; u[j * 4 + e] = q; ss += q * q; }
        }
    }
#pragma unroll
    for (int off = 32; off; off >>= 1) ss += __shfl_xor(ss, off);

    const float n1 = fmaxf(sqrtf(ss), 1e-15f);
    const float ny = fminf(fast_tanh(n1), 0.996f);        // ||proj(expmap0(u))||
    const float g = (ny * __builtin_amdgcn_rcpf(n1)) *
                    (fast_atanh(ny) * __builtin_amdgcn_rcpf(fmaxf(ny, 1e-15f)));

    float ss2 = 0.f;
#pragma unroll
    for (int i = 0; i < 64; ++i) { float q = fast_tanh(u[i] * g); u[i] = q; ss2 += q * q; }
#pragma unroll
    for (int off = 32; off; off >>= 1) ss2 += __shfl_xor(ss2, off);

    const float n3 = fmaxf(sqrtf(ss2), 1e-15f);
    const float s3 = fminf(fast_tanh(n3), 0.996f) * __builtin_amdgcn_rcpf(n3);
    float* orow = out + (size_t)row * GN;
#pragma unroll
    for (int j = 0; j < 16; ++j) {
        f32x4 o;
#pragma unroll
        for (int e = 0; e < 4; ++e) o[e] = u[j * 4 + e] * s3;
        *(f32x4*)(orow + (size_t)(j * 64 + lane) * 4) = o;
    }
}

extern "C" void kernel_launch(void* const* d_in, const int* in_sizes, int n_in,
                              void* d_out, int out_size, void* d_ws, size_t ws_size,
                              hipStream_t stream) {
    const float* x = (const float*)d_in[0];
    const float* W = (const float*)d_in[1];
    const float* b = (const float*)d_in[2];
    float* out = (float*)d_out;

    unsigned short* t_bf = (unsigned short*)d_ws;
    unsigned short* W_bf = t_bf + (size_t)GM * GK;
    unsigned short* C_bf = W_bf + (size_t)GN * GK;
    const size_t need_bf16c = ((size_t)GM * GK + (size_t)GN * GK + (size_t)GM * GN) * 2;
    const bool bf16c = ws_size >= need_bf16c;

    pre_kernel<<<2048 + 1024, 256, 0, stream>>>(x, W, t_bf, W_bf);
    const int nwg = (GM / BM) * (GN / BN);      // 512, divisible by 8
    if (bf16c) {
        gemm_kernel<true><<<nwg, 512, 0, stream>>>(t_bf, W_bf, (void*)C_bf);
        epilogue_kernel<true><<<2048, 256, 0, stream>>>((const void*)C_bf, b, out);
    } else {
        gemm_kernel<false><<<nwg, 512, 0, stream>>>(t_bf, W_bf, (void*)out);
        epilogue_kernel<false><<<2048, 256, 0, stream>>>((const void*)out, b, out);
    }
}